// Round 3
// baseline (95.636 us; speedup 1.0000x reference)
//
#include <hip/hip_runtime.h>

constexpr float EPS_LN = 1e-5f;

using f32x4 = __attribute__((ext_vector_type(4))) float;
using s16x8 = __attribute__((ext_vector_type(8))) short;

__device__ __forceinline__ short f2bf(float f) {
  union { float f; unsigned u; } v; v.f = f;
  unsigned r = v.u + 0x7fff + ((v.u >> 16) & 1);
  return (short)(r >> 16);
}

__device__ __forceinline__ s16x8 cvt8(float4 a, float4 b) {
  s16x8 r;
  r[0] = f2bf(a.x); r[1] = f2bf(a.y); r[2] = f2bf(a.z); r[3] = f2bf(a.w);
  r[4] = f2bf(b.x); r[5] = f2bf(b.y); r[6] = f2bf(b.z); r[7] = f2bf(b.w);
  return r;
}

#define MFMA(a, b, c) __builtin_amdgcn_mfma_f32_16x16x32_bf16((a), (b), (c), 0, 0, 0)

// async global->LDS, 16B per lane; dest = base + lane*16 (HW), src per-lane.
__device__ __forceinline__ void gld_lds16(const void* g, void* l) {
  __builtin_amdgcn_global_load_lds(
      (const __attribute__((address_space(1))) unsigned int*)g,
      (__attribute__((address_space(3))) unsigned int*)l, 16, 0, 0);
}

struct P {
  const int* uid;
  const float *qe, *le, *tab;
  const float *Wu0, *bu0, *Wq0, *bq0, *Wl0, *bl0, *g0, *be0;
  const float *Wu1, *bu1, *Wq1, *bq1, *Wl1, *bl1, *g1, *be1;
  const float *w1, *b1, *w2, *b2;
  short *wt0u, *wt0q, *wt0l, *wt1u, *wt1q, *wt1l, *w1tU, *w1tL;
  float *lw, *out;
};

// Stage one 32k x 256n bf16 chunk (16KB) of wt[n][k] into dst.
// piece pidx = (kg*256 + row), 16B each; wave w stages kg == w.
template<int NK>
__device__ __forceinline__ void stage_chunk(const short* __restrict__ wt, int kk,
                                            short* dst, int w, int lane) {
  #pragma unroll
  for (int s = 0; s < 4; ++s) {
    const int i = w * 4 + s;
    const int pidx = i * 64 + lane;
    const int row = pidx & 255, kg = pidx >> 8;
    gld_lds16(wt + (size_t)row * (NK * 32) + kk * 32 + kg * 8, dst + (size_t)i * 512);
  }
}

// acc[n] += A(16xNK*32) * wt(n-major)[c0+n*16..][k]; A frags in regs (aF[kk]).
// Double-buffered LDS staging with counted vmcnt(4).
template<int NK>
__device__ __forceinline__ void staged_gemm(const short* __restrict__ wt,
                                            const s16x8* aF,
                                            short* sbuf0, short* sbuf1,
                                            int w, int lane, int lr, int lg, int c0,
                                            f32x4 acc[4]) {
  stage_chunk<NK>(wt, 0, sbuf0, w, lane);
  #pragma unroll
  for (int kk = 0; kk < NK; ++kk) {
    short* cur = (kk & 1) ? sbuf1 : sbuf0;
    short* nxt = (kk & 1) ? sbuf0 : sbuf1;
    if (kk + 1 < NK) {
      stage_chunk<NK>(wt, kk + 1, nxt, w, lane);
      asm volatile("s_waitcnt vmcnt(4)" ::: "memory");
    } else {
      asm volatile("s_waitcnt vmcnt(0)" ::: "memory");
    }
    __syncthreads();
    #pragma unroll
    for (int n = 0; n < 4; ++n) {
      const s16x8 bf = *(const s16x8*)&cur[(lg * 256 + c0 + n * 16 + lr) * 8];
      acc[n] = MFMA(aF[kk], bf, acc[n]);
    }
    __syncthreads();
  }
}

// LN over 256 cols; in-place on z[n][r] (col=c0+n*16+lr, row=lg*4+r).
__device__ __forceinline__ void ln16(float z[4][4], int tid, int w, int lr, int lg,
                                     int c0, const float* __restrict__ g,
                                     const float* __restrict__ be,
                                     float (*ssum)[16], float (*ssq)[16],
                                     float* mub, float* rsb) {
  __syncthreads();
  float s1[4] = {0, 0, 0, 0}, s2[4] = {0, 0, 0, 0};
  #pragma unroll
  for (int n = 0; n < 4; ++n)
    #pragma unroll
    for (int r = 0; r < 4; ++r) { s1[r] += z[n][r]; s2[r] += z[n][r] * z[n][r]; }
  #pragma unroll
  for (int off = 1; off < 16; off <<= 1)
    #pragma unroll
    for (int r = 0; r < 4; ++r) {
      s1[r] += __shfl_xor(s1[r], off, 64);
      s2[r] += __shfl_xor(s2[r], off, 64);
    }
  if (lr == 0) {
    #pragma unroll
    for (int r = 0; r < 4; ++r) { ssum[w][lg * 4 + r] = s1[r]; ssq[w][lg * 4 + r] = s2[r]; }
  }
  __syncthreads();
  if (tid < 16) {
    float S1 = 0, S2 = 0;
    #pragma unroll
    for (int ww = 0; ww < 4; ++ww) { S1 += ssum[ww][tid]; S2 += ssq[ww][tid]; }
    float mu = S1 * (1.f / 256.f);
    float var = S2 * (1.f / 256.f) - mu * mu;
    mub[tid] = mu;
    rsb[tid] = rsqrtf(var + EPS_LN);
  }
  __syncthreads();
  #pragma unroll
  for (int n = 0; n < 4; ++n) {
    const int c = c0 + n * 16 + lr;
    const float gv = g[c], bv = be[c];
    #pragma unroll
    for (int r = 0; r < 4; ++r) {
      const int rr = lg * 4 + r;
      z[n][r] = gv * (z[n][r] - mub[rr]) * rsb[rr] + bv;
    }
  }
}

__device__ __forceinline__ void bias2(const f32x4 acc[4], const float* __restrict__ b,
                                      int c0, int lr, float z[4][4]) {
  #pragma unroll
  for (int n = 0; n < 4; ++n) {
    const float bv = b[c0 + n * 16 + lr];
    #pragma unroll
    for (int r = 0; r < 4; ++r) z[n][r] = 2.f * (acc[n][r] + bv);
  }
}

__device__ __forceinline__ void store_y(const float z[4][4], short* y_s,
                                        int c0, int lr, int lg) {
  #pragma unroll
  for (int n = 0; n < 4; ++n)
    #pragma unroll
    for (int r = 0; r < 4; ++r)
      y_s[(lg * 4 + r) * 264 + c0 + n * 16 + lr] = f2bf(z[n][r]);
}

__device__ __forceinline__ void load_aF(const short* y_s, s16x8* aF, int lr, int lg) {
  #pragma unroll
  for (int kk = 0; kk < 8; ++kk)
    aF[kk] = *(const s16x8*)&y_s[lr * 264 + kk * 32 + lg * 8];
}

// ---- K0: transpose+cast all weights to bf16 wt[n][k] ----
__global__ __launch_bounds__(256) void k0_kernel(P p) {
  const int bx = blockIdx.x, tid = threadIdx.x;
  if (bx < 1152) {  // K=384 matrices
    const int m = bx / 384;
    const int o = (bx - m * 384) * 256 + tid;
    const int n = o / 384, k = o - n * 384;
    const float* W = (m == 0) ? p.Wu0 : (m == 1) ? p.Wq0 : p.Wl0;
    short* T = (m == 0) ? p.wt0u : (m == 1) ? p.wt0q : p.wt0l;
    T[o] = f2bf(W[(size_t)k * 256 + n]);
  } else {  // K=256 matrices
    const int m = (bx - 1152) >> 8;
    const int o = ((bx - 1152) & 255) * 256 + tid;
    const int n = o >> 8, k = o & 255;
    const float* W;
    short* T;
    int krow = k;
    if (m == 0)      { W = p.Wu1; T = p.wt1u; }
    else if (m == 1) { W = p.Wq1; T = p.wt1q; }
    else if (m == 2) { W = p.Wl1; T = p.wt1l; }
    else if (m == 3) { W = p.w1;  T = p.w1tU; krow = 256 + k; }
    else             { W = p.w1;  T = p.w1tL; }
    T[o] = f2bf(W[(size_t)krow * 256 + n]);
  }
}

// ---- K1: llm path (4 blocks x 16 rows) -> lw fp32 [64][256] ----
__global__ __launch_bounds__(256, 1) void k1_kernel(P p) {
  __shared__ __align__(16) short sbuf0[8192], sbuf1[8192];
  __shared__ __align__(16) short y_s[16 * 264];
  __shared__ float ssum[4][16], ssq[4][16], mub[16], rsb[16];
  const int tid = threadIdx.x, w = tid >> 6, lane = tid & 63;
  const int lr = lane & 15, lg = lane >> 4;
  const int c0 = w * 64;
  const int r0 = blockIdx.x * 16;

  s16x8 aF[12];
  {
    const float4* ar = (const float4*)(p.le + (size_t)(r0 + lr) * 384);
    #pragma unroll
    for (int kk = 0; kk < 12; ++kk) aF[kk] = cvt8(ar[kk * 8 + lg * 2], ar[kk * 8 + lg * 2 + 1]);
  }
  f32x4 acc[4];
  const f32x4 z4 = {0.f, 0.f, 0.f, 0.f};
  #pragma unroll
  for (int n = 0; n < 4; ++n) acc[n] = z4;
  staged_gemm<12>(p.wt0l, aF, sbuf0, sbuf1, w, lane, lr, lg, c0, acc);
  float z[4][4];
  bias2(acc, p.bl0, c0, lr, z);
  ln16(z, tid, w, lr, lg, c0, p.g0, p.be0, ssum, ssq, mub, rsb);
  store_y(z, y_s, c0, lr, lg);
  __syncthreads();
  s16x8 aH[8];
  load_aF(y_s, aH, lr, lg);
  #pragma unroll
  for (int n = 0; n < 4; ++n) acc[n] = z4;
  staged_gemm<8>(p.wt1l, aH, sbuf0, sbuf1, w, lane, lr, lg, c0, acc);
  bias2(acc, p.bl1, c0, lr, z);
  ln16(z, tid, w, lr, lg, c0, p.g1, p.be1, ssum, ssq, mub, rsb);
  store_y(z, y_s, c0, lr, lg);
  __syncthreads();
  load_aF(y_s, aH, lr, lg);
  #pragma unroll
  for (int n = 0; n < 4; ++n) acc[n] = z4;
  staged_gemm<8>(p.w1tL, aH, sbuf0, sbuf1, w, lane, lr, lg, c0, acc);
  #pragma unroll
  for (int n = 0; n < 4; ++n) {
    const int c = c0 + n * 16 + lr;
    const float bv = p.b1[c];
    #pragma unroll
    for (int r = 0; r < 4; ++r)
      p.lw[(size_t)(r0 + lg * 4 + r) * 256 + c] = acc[n][r] + bv;
  }
}

// ---- K2: fused u/q path + score (256 blocks x 16 batch rows) ----
__global__ __launch_bounds__(256, 1) void k2_kernel(P p) {
  __shared__ __align__(16) short sbuf0[8192], sbuf1[8192];
  __shared__ __align__(16) short y_s[16 * 264];
  __shared__ __align__(16) float lw_s[64 * 256];
  __shared__ __align__(16) float uqw_s[16 * 260];
  __shared__ float w2s[256];
  __shared__ float ssum[4][16], ssq[4][16], mub[16], rsb[16];

  const int tid = threadIdx.x, w = tid >> 6, lane = tid & 63;
  const int lr = lane & 15, lg = lane >> 4;
  const int c0 = w * 64;
  const int r0 = blockIdx.x * 16;

  // stage lw (64KB) via global_load_lds with XOR-swizzled source (T21 both-sides)
  #pragma unroll
  for (int s = 0; s < 16; ++s) {
    const int i = w * 16 + s;
    const int pidx = i * 64 + lane;
    const int row = pidx >> 6, c4 = pidx & 63;
    gld_lds16(p.lw + (size_t)row * 256 + ((c4 ^ (row & 7)) << 2),
              (char*)lw_s + (size_t)i * 1024);
  }
  w2s[tid] = p.w2[tid];

  const f32x4 z4 = {0.f, 0.f, 0.f, 0.f};
  s16x8 aF[12];
  s16x8 aH[8];
  float z[4][4];

  // ---- u: layer0 ----
  {
    const int uid = p.uid[r0 + lr];
    const float4* ar = (const float4*)(p.tab + (size_t)uid * 384);
    #pragma unroll
    for (int kk = 0; kk < 12; ++kk) aF[kk] = cvt8(ar[kk * 8 + lg * 2], ar[kk * 8 + lg * 2 + 1]);
  }
  f32x4 acc[4];
  #pragma unroll
  for (int n = 0; n < 4; ++n) acc[n] = z4;
  staged_gemm<12>(p.wt0u, aF, sbuf0, sbuf1, w, lane, lr, lg, c0, acc);
  bias2(acc, p.bu0, c0, lr, z);
  ln16(z, tid, w, lr, lg, c0, p.g0, p.be0, ssum, ssq, mub, rsb);
  store_y(z, y_s, c0, lr, lg);
  __syncthreads();
  load_aF(y_s, aH, lr, lg);
  // ---- u: layer1 (hold accU) ----
  f32x4 accU[4];
  #pragma unroll
  for (int n = 0; n < 4; ++n) accU[n] = z4;
  staged_gemm<8>(p.wt1u, aH, sbuf0, sbuf1, w, lane, lr, lg, c0, accU);

  // ---- q: layer0 ----
  {
    const float4* ar = (const float4*)(p.qe + (size_t)(r0 + lr) * 384);
    #pragma unroll
    for (int kk = 0; kk < 12; ++kk) aF[kk] = cvt8(ar[kk * 8 + lg * 2], ar[kk * 8 + lg * 2 + 1]);
  }
  #pragma unroll
  for (int n = 0; n < 4; ++n) acc[n] = z4;
  staged_gemm<12>(p.wt0q, aF, sbuf0, sbuf1, w, lane, lr, lg, c0, acc);
  bias2(acc, p.bq0, c0, lr, z);
  ln16(z, tid, w, lr, lg, c0, p.g0, p.be0, ssum, ssq, mub, rsb);
  store_y(z, y_s, c0, lr, lg);
  __syncthreads();
  load_aF(y_s, aH, lr, lg);
  // ---- q: layer1 ----
  f32x4 accQ[4];
  #pragma unroll
  for (int n = 0; n < 4; ++n) accQ[n] = z4;
  staged_gemm<8>(p.wt1q, aH, sbuf0, sbuf1, w, lane, lr, lg, c0, accQ);

  // ---- layer1 LNs + add -> uq ----
  float zq[4][4];
  bias2(accU, p.bu1, c0, lr, z);
  ln16(z, tid, w, lr, lg, c0, p.g1, p.be1, ssum, ssq, mub, rsb);
  bias2(accQ, p.bq1, c0, lr, zq);
  ln16(zq, tid, w, lr, lg, c0, p.g1, p.be1, ssum, ssq, mub, rsb);
  #pragma unroll
  for (int n = 0; n < 4; ++n)
    #pragma unroll
    for (int r = 0; r < 4; ++r) z[n][r] += zq[n][r];
  store_y(z, y_s, c0, lr, lg);
  __syncthreads();
  load_aF(y_s, aH, lr, lg);

  // ---- GEMM2: uqw = uq @ w1[256:,:] ----
  #pragma unroll
  for (int n = 0; n < 4; ++n) acc[n] = z4;
  staged_gemm<8>(p.w1tU, aH, sbuf0, sbuf1, w, lane, lr, lg, c0, acc);
  #pragma unroll
  for (int n = 0; n < 4; ++n) {
    const int c = c0 + n * 16 + lr;
    #pragma unroll
    for (int r = 0; r < 4; ++r)
      uqw_s[(lg * 4 + r) * 260 + c] = acc[n][r];
  }
  __syncthreads();  // uqw_s ready; lw_s already drained by last vmcnt(0)+barrier

  // ---- score: out[b][l] = sum_j relu(lw[l][j]+uqw[b][j])*w2[j] + b2 ----
  const float b2v = p.b2[0];
  const int l = lane;
  float sacc[4] = {0.f, 0.f, 0.f, 0.f};
  #pragma unroll 4
  for (int jj = 0; jj < 64; ++jj) {
    const float4 lwv = *(const float4*)&lw_s[l * 256 + ((jj ^ (l & 7)) << 2)];
    const float4 w2v = *(const float4*)&w2s[jj * 4];
    #pragma unroll
    for (int bi = 0; bi < 4; ++bi) {
      const float4 uqv = *(const float4*)&uqw_s[(w * 4 + bi) * 260 + jj * 4];
      sacc[bi] += fmaxf(lwv.x + uqv.x, 0.f) * w2v.x;
      sacc[bi] += fmaxf(lwv.y + uqv.y, 0.f) * w2v.y;
      sacc[bi] += fmaxf(lwv.z + uqv.z, 0.f) * w2v.z;
      sacc[bi] += fmaxf(lwv.w + uqv.w, 0.f) * w2v.w;
    }
  }
  #pragma unroll
  for (int bi = 0; bi < 4; ++bi)
    p.out[(size_t)(r0 + w * 4 + bi) * 64 + l] = sacc[bi] + b2v;
}

extern "C" void kernel_launch(void* const* d_in, const int* in_sizes, int n_in,
                              void* d_out, int out_size, void* d_ws, size_t ws_size,
                              hipStream_t stream) {
  (void)in_sizes; (void)n_in; (void)out_size; (void)ws_size;
  P p;
  p.uid = (const int*)d_in[0];
  p.qe  = (const float*)d_in[1];
  p.le  = (const float*)d_in[2];
  p.tab = (const float*)d_in[3];
  p.Wu0 = (const float*)d_in[4];  p.bu0 = (const float*)d_in[5];
  p.Wq0 = (const float*)d_in[6];  p.bq0 = (const float*)d_in[7];
  p.Wl0 = (const float*)d_in[8];  p.bl0 = (const float*)d_in[9];
  p.g0  = (const float*)d_in[10]; p.be0 = (const float*)d_in[11];
  p.Wu1 = (const float*)d_in[12]; p.bu1 = (const float*)d_in[13];
  p.Wq1 = (const float*)d_in[14]; p.bq1 = (const float*)d_in[15];
  p.Wl1 = (const float*)d_in[16]; p.bl1 = (const float*)d_in[17];
  p.g1  = (const float*)d_in[18]; p.be1 = (const float*)d_in[19];
  p.w1  = (const float*)d_in[20]; p.b1  = (const float*)d_in[21];
  p.w2  = (const float*)d_in[22]; p.b2  = (const float*)d_in[23];

  short* wsS = (short*)d_ws;
  size_t o = 0;
  p.wt0u = wsS + o; o += 98304;   // 256x384
  p.wt0q = wsS + o; o += 98304;
  p.wt0l = wsS + o; o += 98304;
  p.wt1u = wsS + o; o += 65536;   // 256x256
  p.wt1q = wsS + o; o += 65536;
  p.wt1l = wsS + o; o += 65536;
  p.w1tU = wsS + o; o += 65536;   // w1[256:512] transposed
  p.w1tL = wsS + o; o += 65536;   // w1[0:256] transposed
  p.lw  = (float*)(wsS + o);      // 64x256 fp32, byte offset 1245184 (16B aligned)
  p.out = (float*)d_out;

  hipLaunchKernelGGL(k0_kernel, dim3(2432), dim3(256), 0, stream, p);
  hipLaunchKernelGGL(k1_kernel, dim3(4), dim3(256), 0, stream, p);
  hipLaunchKernelGGL(k2_kernel, dim3(256), dim3(256), 0, stream, p);
}

// Round 6
// 81.746 us; speedup vs baseline: 1.1699x; 1.1699x over previous
//
#include <hip/hip_runtime.h>

constexpr float EPS_LN = 1e-5f;

using f32x4 = __attribute__((ext_vector_type(4))) float;
using s16x8 = __attribute__((ext_vector_type(8))) short;

__device__ __forceinline__ short f2bf(float f) {
  union { float f; unsigned u; } v; v.f = f;
  unsigned r = v.u + 0x7fff + ((v.u >> 16) & 1);
  return (short)(r >> 16);
}

__device__ __forceinline__ s16x8 cvt8(float4 a, float4 b) {
  s16x8 r;
  r[0] = f2bf(a.x); r[1] = f2bf(a.y); r[2] = f2bf(a.z); r[3] = f2bf(a.w);
  r[4] = f2bf(b.x); r[5] = f2bf(b.y); r[6] = f2bf(b.z); r[7] = f2bf(b.w);
  return r;
}

#define MFMA(a, b, c) __builtin_amdgcn_mfma_f32_16x16x32_bf16((a), (b), (c), 0, 0, 0)

__device__ __forceinline__ void gld_lds16(const void* g, void* l) {
  __builtin_amdgcn_global_load_lds(
      (const __attribute__((address_space(1))) unsigned int*)g,
      (__attribute__((address_space(3))) unsigned int*)l, 16, 0, 0);
}

__device__ __forceinline__ void vw0() { asm volatile("s_waitcnt vmcnt(0)" ::: "memory"); }
__device__ __forceinline__ void vw4() { asm volatile("s_waitcnt vmcnt(4)" ::: "memory"); }

struct P {
  const int* uid;
  const float *qe, *le, *tab;
  const float *Wu0, *bu0, *Wq0, *bq0, *Wl0, *bl0, *g0, *be0;
  const float *Wu1, *bu1, *Wq1, *bq1, *Wl1, *bl1, *g1, *be1;
  const float *w1, *b1, *w2, *b2;
  short *wt0u, *wt0q, *wt0l, *wt1u, *wt1q, *wt1l, *w1tU, *w1tL;
  short *y0, *uqB;
  float *lw, *out;
};

// Block-shared staging of one 32k x 256n bf16 chunk (16KB) of wt[n][k].
// piece pidx = kg*256 + row (16B each); wave w stages pieces w*4..w*4+3.
// VERIFIED-correct primitive (round 3): chunk groups are separated by
// __syncthreads() inside staged_gemm, which pins VMEM issue order, making
// the counted vmcnt(4) sound (barrier-free variants raced — rounds 4/5).
template<int NK>
__device__ __forceinline__ void stage_chunk(const short* __restrict__ wt, int kk,
                                            short* dst, int w, int lane) {
  #pragma unroll
  for (int s = 0; s < 4; ++s) {
    const int i = w * 4 + s;
    const int pidx = i * 64 + lane;
    const int row = pidx & 255, kg = pidx >> 8;
    gld_lds16(wt + (size_t)row * (NK * 32) + kk * 32 + kg * 8, dst + (size_t)i * 512);
  }
}

// acc[n] += A(16 x NK*32) * wt[c0+n*16+..][k]; A frags in regs (aF[kk]).
// Double-buffered block-shared LDS staging, counted vmcnt(4), 2 barriers/step.
template<int NK>
__device__ __forceinline__ void staged_gemm(const short* __restrict__ wt,
                                            const s16x8* aF,
                                            short* sbuf0, short* sbuf1,
                                            int w, int lane, int lr, int lg, int c0,
                                            f32x4 acc[4]) {
  stage_chunk<NK>(wt, 0, sbuf0, w, lane);
  #pragma unroll
  for (int kk = 0; kk < NK; ++kk) {
    short* cur = (kk & 1) ? sbuf1 : sbuf0;
    short* nxt = (kk & 1) ? sbuf0 : sbuf1;
    if (kk + 1 < NK) {
      stage_chunk<NK>(wt, kk + 1, nxt, w, lane);
      vw4();
    } else {
      vw0();
    }
    __syncthreads();
    #pragma unroll
    for (int n = 0; n < 4; ++n) {
      const s16x8 bf = *(const s16x8*)&cur[(lg * 256 + c0 + n * 16 + lr) * 8];
      acc[n] = MFMA(aF[kk], bf, acc[n]);
    }
    __syncthreads();
  }
}

// LayerNorm over 256 cols; in-place on z[n][r] (col=c0+n*16+lr, row=lg*4+r).
__device__ __forceinline__ void ln16(float z[4][4], int tid, int w, int lr, int lg,
                                     int c0, const float* __restrict__ g,
                                     const float* __restrict__ be,
                                     float (*ssum)[16], float (*ssq)[16],
                                     float* mub, float* rsb) {
  __syncthreads();
  float s1[4] = {0, 0, 0, 0}, s2[4] = {0, 0, 0, 0};
  #pragma unroll
  for (int n = 0; n < 4; ++n)
    #pragma unroll
    for (int r = 0; r < 4; ++r) { s1[r] += z[n][r]; s2[r] += z[n][r] * z[n][r]; }
  #pragma unroll
  for (int off = 1; off < 16; off <<= 1)
    #pragma unroll
    for (int r = 0; r < 4; ++r) {
      s1[r] += __shfl_xor(s1[r], off, 64);
      s2[r] += __shfl_xor(s2[r], off, 64);
    }
  if (lr == 0) {
    #pragma unroll
    for (int r = 0; r < 4; ++r) { ssum[w][lg * 4 + r] = s1[r]; ssq[w][lg * 4 + r] = s2[r]; }
  }
  __syncthreads();
  if (tid < 16) {
    float S1 = 0, S2 = 0;
    #pragma unroll
    for (int ww = 0; ww < 4; ++ww) { S1 += ssum[ww][tid]; S2 += ssq[ww][tid]; }
    float mu = S1 * (1.f / 256.f);
    float var = S2 * (1.f / 256.f) - mu * mu;
    mub[tid] = mu;
    rsb[tid] = rsqrtf(var + EPS_LN);
  }
  __syncthreads();
  #pragma unroll
  for (int n = 0; n < 4; ++n) {
    const int c = c0 + n * 16 + lr;
    const float gv = g[c], bv = be[c];
    #pragma unroll
    for (int r = 0; r < 4; ++r) {
      const int rr = lg * 4 + r;
      z[n][r] = gv * (z[n][r] - mub[rr]) * rsb[rr] + bv;
    }
  }
}

__device__ __forceinline__ void bias2(const f32x4 acc[4], const float* __restrict__ b,
                                      int c0, int lr, float z[4][4]) {
  #pragma unroll
  for (int n = 0; n < 4; ++n) {
    const float bv = b[c0 + n * 16 + lr];
    #pragma unroll
    for (int r = 0; r < 4; ++r) z[n][r] = 2.f * (acc[n][r] + bv);
  }
}

__device__ __forceinline__ void store_y(const float z[4][4], short* y_s,
                                        int c0, int lr, int lg) {
  #pragma unroll
  for (int n = 0; n < 4; ++n)
    #pragma unroll
    for (int r = 0; r < 4; ++r)
      y_s[(lg * 4 + r) * 264 + c0 + n * 16 + lr] = f2bf(z[n][r]);
}

__device__ __forceinline__ void load_aF(const short* y_s, s16x8* aF, int lr, int lg) {
  #pragma unroll
  for (int kk = 0; kk < 8; ++kk)
    aF[kk] = *(const s16x8*)&y_s[lr * 264 + kk * 32 + lg * 8];
}

// ---- K0: transpose+cast all weights to bf16 wt[n][k] ----
__global__ __launch_bounds__(256) void k0_kernel(P p) {
  const int bx = blockIdx.x, tid = threadIdx.x;
  if (bx < 1152) {  // K=384 matrices
    const int m = bx / 384;
    const int o = (bx - m * 384) * 256 + tid;
    const int n = o / 384, k = o - n * 384;
    const float* W = (m == 0) ? p.Wu0 : (m == 1) ? p.Wq0 : p.Wl0;
    short* T = (m == 0) ? p.wt0u : (m == 1) ? p.wt0q : p.wt0l;
    T[o] = f2bf(W[(size_t)k * 256 + n]);
  } else {  // K=256 matrices
    const int m = (bx - 1152) >> 8;
    const int o = ((bx - 1152) & 255) * 256 + tid;
    const int n = o >> 8, k = o & 255;
    const float* W;
    short* T;
    int krow = k;
    if (m == 0)      { W = p.Wu1; T = p.wt1u; }
    else if (m == 1) { W = p.Wq1; T = p.wt1q; }
    else if (m == 2) { W = p.Wl1; T = p.wt1l; }
    else if (m == 3) { W = p.w1;  T = p.w1tU; krow = 256 + k; }
    else             { W = p.w1;  T = p.w1tL; }
    T[o] = f2bf(W[(size_t)krow * 256 + n]);
  }
}

// ---- kA: layer0 for u (blocks 0..255) and q (256..511) -> y0 bf16 [8192][256]
__global__ __launch_bounds__(256) void ka_kernel(P p) {
  __shared__ __align__(16) short sbuf0[8192], sbuf1[8192];
  __shared__ __align__(16) short y_s[16 * 264];
  __shared__ float ssum[4][16], ssq[4][16], mub[16], rsb[16];
  const int tid = threadIdx.x, w = tid >> 6, lane = tid & 63;
  const int lr = lane & 15, lg = lane >> 4;
  const int c0 = w * 64;
  const int t = blockIdx.x;
  const int r0 = t * 16;
  const float* arow;
  const short* wt;
  const float* bias;
  if (t < 256) { arow = p.tab + (size_t)p.uid[r0 + lr] * 384; wt = p.wt0u; bias = p.bu0; }
  else         { arow = p.qe + (size_t)(r0 - 4096 + lr) * 384; wt = p.wt0q; bias = p.bq0; }
  s16x8 aF[12];
  #pragma unroll
  for (int kk = 0; kk < 12; ++kk)
    aF[kk] = cvt8(*(const float4*)(arow + kk * 32 + lg * 8),
                  *(const float4*)(arow + kk * 32 + lg * 8 + 4));
  vw0();  // drain A loads so staged_gemm's vmcnt counting starts clean
  const f32x4 z4 = {0.f, 0.f, 0.f, 0.f};
  f32x4 acc[4] = {z4, z4, z4, z4};
  staged_gemm<12>(wt, aF, sbuf0, sbuf1, w, lane, lr, lg, c0, acc);
  float z[4][4];
  bias2(acc, bias, c0, lr, z);
  ln16(z, tid, w, lr, lg, c0, p.g0, p.be0, ssum, ssq, mub, rsb);
  store_y(z, y_s, c0, lr, lg);
  __syncthreads();
  #pragma unroll
  for (int i = 0; i < 2; ++i) {
    const int idx = i * 256 + tid;  // 512 pieces of 16B
    const int row = idx >> 5, cc = (idx & 31) * 8;
    *(s16x8*)(p.y0 + (size_t)(r0 + row) * 256 + cc) = *(const s16x8*)&y_s[row * 264 + cc];
  }
}

// ---- kB: blocks 0..3 = llm full chain -> lw; blocks 4..259 = u/q layer1+add -> uqB
__global__ __launch_bounds__(256) void kb_kernel(P p) {
  __shared__ __align__(16) short sbuf0[8192], sbuf1[8192];
  __shared__ __align__(16) short y_s[16 * 264];
  __shared__ float ssum[4][16], ssq[4][16], mub[16], rsb[16];
  const int tid = threadIdx.x, w = tid >> 6, lane = tid & 63;
  const int lr = lane & 15, lg = lane >> 4;
  const int c0 = w * 64;
  const int bx = blockIdx.x;
  const f32x4 z4 = {0.f, 0.f, 0.f, 0.f};

  if (bx >= 4) {
    const int r0 = (bx - 4) * 16;
    s16x8 aF[8];
    {
      const s16x8* ap = (const s16x8*)(p.y0 + (size_t)(r0 + lr) * 256);
      #pragma unroll
      for (int kk = 0; kk < 8; ++kk) aF[kk] = ap[kk * 4 + lg];
    }
    vw0();
    f32x4 accU[4] = {z4, z4, z4, z4};
    staged_gemm<8>(p.wt1u, aF, sbuf0, sbuf1, w, lane, lr, lg, c0, accU);
    {
      const s16x8* ap = (const s16x8*)(p.y0 + (size_t)(4096 + r0 + lr) * 256);
      #pragma unroll
      for (int kk = 0; kk < 8; ++kk) aF[kk] = ap[kk * 4 + lg];
    }
    vw0();
    f32x4 accQ[4] = {z4, z4, z4, z4};
    staged_gemm<8>(p.wt1q, aF, sbuf0, sbuf1, w, lane, lr, lg, c0, accQ);
    float z[4][4], zq[4][4];
    bias2(accU, p.bu1, c0, lr, z);
    ln16(z, tid, w, lr, lg, c0, p.g1, p.be1, ssum, ssq, mub, rsb);
    bias2(accQ, p.bq1, c0, lr, zq);
    ln16(zq, tid, w, lr, lg, c0, p.g1, p.be1, ssum, ssq, mub, rsb);
    #pragma unroll
    for (int n = 0; n < 4; ++n)
      #pragma unroll
      for (int r = 0; r < 4; ++r) z[n][r] += zq[n][r];
    store_y(z, y_s, c0, lr, lg);
    __syncthreads();
    #pragma unroll
    for (int i = 0; i < 2; ++i) {
      const int idx = i * 256 + tid;
      const int row = idx >> 5, cc = (idx & 31) * 8;
      *(s16x8*)(p.uqB + (size_t)(r0 + row) * 256 + cc) = *(const s16x8*)&y_s[row * 264 + cc];
    }
  } else {
    const int r0 = bx * 16;
    const float* arow = p.le + (size_t)(r0 + lr) * 384;
    s16x8 aF[12];
    #pragma unroll
    for (int kk = 0; kk < 12; ++kk)
      aF[kk] = cvt8(*(const float4*)(arow + kk * 32 + lg * 8),
                    *(const float4*)(arow + kk * 32 + lg * 8 + 4));
    vw0();
    f32x4 acc[4] = {z4, z4, z4, z4};
    staged_gemm<12>(p.wt0l, aF, sbuf0, sbuf1, w, lane, lr, lg, c0, acc);
    float z[4][4];
    bias2(acc, p.bl0, c0, lr, z);
    ln16(z, tid, w, lr, lg, c0, p.g0, p.be0, ssum, ssq, mub, rsb);
    store_y(z, y_s, c0, lr, lg);
    __syncthreads();
    s16x8 aH[8];
    load_aF(y_s, aH, lr, lg);
    #pragma unroll
    for (int n = 0; n < 4; ++n) acc[n] = z4;
    staged_gemm<8>(p.wt1l, aH, sbuf0, sbuf1, w, lane, lr, lg, c0, acc);
    bias2(acc, p.bl1, c0, lr, z);
    ln16(z, tid, w, lr, lg, c0, p.g1, p.be1, ssum, ssq, mub, rsb);
    store_y(z, y_s, c0, lr, lg);
    __syncthreads();
    load_aF(y_s, aH, lr, lg);
    #pragma unroll
    for (int n = 0; n < 4; ++n) acc[n] = z4;
    staged_gemm<8>(p.w1tL, aH, sbuf0, sbuf1, w, lane, lr, lg, c0, acc);
    #pragma unroll
    for (int n = 0; n < 4; ++n) {
      const int c = c0 + n * 16 + lr;
      const float bv = p.b1[c];
      #pragma unroll
      for (int r = 0; r < 4; ++r)
        p.lw[(size_t)(r0 + lg * 4 + r) * 256 + c] = acc[n][r] + bv;
    }
  }
}

// ---- kC: GEMM2 (uq @ w1[256:,:]) kept in LDS + fused score -> out ----
__global__ __launch_bounds__(256, 1) void kc_kernel(P p) {
  __shared__ __align__(16) short sbuf0[8192], sbuf1[8192];
  __shared__ __align__(16) float lw_s[64 * 256];
  __shared__ __align__(16) float uqw_s[16 * 260];
  __shared__ float w2s[256];
  const int tid = threadIdx.x, w = tid >> 6, lane = tid & 63;
  const int lr = lane & 15, lg = lane >> 4;
  const int c0 = w * 64;
  const int r0 = blockIdx.x * 16;

  // stage lw (64KB fp32) with XOR-swizzled source (both-sides swizzle)
  #pragma unroll
  for (int s = 0; s < 16; ++s) {
    const int i = w * 16 + s;  // lw row
    gld_lds16(p.lw + (size_t)i * 256 + ((lane ^ (i & 7)) << 2),
              (char*)lw_s + (size_t)i * 1024);
  }
  w2s[tid] = p.w2[tid];

  s16x8 aF[8];
  {
    const s16x8* ap = (const s16x8*)(p.uqB + (size_t)(r0 + lr) * 256);
    #pragma unroll
    for (int kk = 0; kk < 8; ++kk) aF[kk] = ap[kk * 4 + lg];
  }
  vw0();  // drains lw staging + A loads; staged_gemm counting starts clean
  const f32x4 z4 = {0.f, 0.f, 0.f, 0.f};
  f32x4 acc[4] = {z4, z4, z4, z4};
  staged_gemm<8>(p.w1tU, aF, sbuf0, sbuf1, w, lane, lr, lg, c0, acc);
  #pragma unroll
  for (int n = 0; n < 4; ++n)
    #pragma unroll
    for (int r = 0; r < 4; ++r)
      uqw_s[(lg * 4 + r) * 260 + c0 + n * 16 + lr] = acc[n][r];
  __syncthreads();

  // score: out[b][l] = sum_j relu(lw[l][j]+uqw[b][j])*w2[j] + b2
  const float b2v = p.b2[0];
  const int l = lane;
  float sacc[4] = {0.f, 0.f, 0.f, 0.f};
  #pragma unroll 4
  for (int jj = 0; jj < 64; ++jj) {
    const float4 lwv = *(const float4*)&lw_s[l * 256 + ((jj ^ (l & 7)) << 2)];
    const float4 w2v = *(const float4*)&w2s[jj * 4];
    #pragma unroll
    for (int bi = 0; bi < 4; ++bi) {
      const float4 uqv = *(const float4*)&uqw_s[(w * 4 + bi) * 260 + jj * 4];
      sacc[bi] += fmaxf(lwv.x + uqv.x, 0.f) * w2v.x;
      sacc[bi] += fmaxf(lwv.y + uqv.y, 0.f) * w2v.y;
      sacc[bi] += fmaxf(lwv.z + uqv.z, 0.f) * w2v.z;
      sacc[bi] += fmaxf(lwv.w + uqv.w, 0.f) * w2v.w;
    }
  }
  #pragma unroll
  for (int bi = 0; bi < 4; ++bi)
    p.out[(size_t)(r0 + w * 4 + bi) * 64 + l] = sacc[bi] + b2v;
}

extern "C" void kernel_launch(void* const* d_in, const int* in_sizes, int n_in,
                              void* d_out, int out_size, void* d_ws, size_t ws_size,
                              hipStream_t stream) {
  (void)in_sizes; (void)n_in; (void)out_size; (void)ws_size;
  P p;
  p.uid = (const int*)d_in[0];
  p.qe  = (const float*)d_in[1];
  p.le  = (const float*)d_in[2];
  p.tab = (const float*)d_in[3];
  p.Wu0 = (const float*)d_in[4];  p.bu0 = (const float*)d_in[5];
  p.Wq0 = (const float*)d_in[6];  p.bq0 = (const float*)d_in[7];
  p.Wl0 = (const float*)d_in[8];  p.bl0 = (const float*)d_in[9];
  p.g0  = (const float*)d_in[10]; p.be0 = (const float*)d_in[11];
  p.Wu1 = (const float*)d_in[12]; p.bu1 = (const float*)d_in[13];
  p.Wq1 = (const float*)d_in[14]; p.bq1 = (const float*)d_in[15];
  p.Wl1 = (const float*)d_in[16]; p.bl1 = (const float*)d_in[17];
  p.g1  = (const float*)d_in[18]; p.be1 = (const float*)d_in[19];
  p.w1  = (const float*)d_in[20]; p.b1  = (const float*)d_in[21];
  p.w2  = (const float*)d_in[22]; p.b2  = (const float*)d_in[23];

  short* wsS = (short*)d_ws;
  size_t o = 0;
  p.wt0u = wsS + o; o += 98304;    // 256x384
  p.wt0q = wsS + o; o += 98304;
  p.wt0l = wsS + o; o += 98304;
  p.wt1u = wsS + o; o += 65536;    // 256x256
  p.wt1q = wsS + o; o += 65536;
  p.wt1l = wsS + o; o += 65536;
  p.w1tU = wsS + o; o += 65536;    // w1[256:512]^T
  p.w1tL = wsS + o; o += 65536;    // w1[0:256]^T
  p.y0   = wsS + o; o += 2097152;  // 8192x256 bf16 (u rows 0..4095, q rows 4096..8191)
  p.uqB  = wsS + o; o += 1048576;  // 4096x256 bf16
  p.lw   = (float*)(wsS + o);      // 64x256 fp32 (16B-aligned byte offset)
  p.out  = (float*)d_out;

  hipLaunchKernelGGL(k0_kernel, dim3(2432), dim3(256), 0, stream, p);
  hipLaunchKernelGGL(ka_kernel, dim3(512), dim3(256), 0, stream, p);
  hipLaunchKernelGGL(kb_kernel, dim3(260), dim3(256), 0, stream, p);
  hipLaunchKernelGGL(kc_kernel, dim3(256), dim3(256), 0, stream, p);
}